// Round 2
// 724.227 us; speedup vs baseline: 1.0422x; 1.0422x over previous
//
#include <hip/hip_runtime.h>
#include <hip/hip_bf16.h>
#include <math.h>

typedef unsigned short u16;
typedef __bf16 bf16x8 __attribute__((ext_vector_type(8)));
typedef float floatx4 __attribute__((ext_vector_type(4)));

#define LORA_SCALING 2.0f   // alpha 32 / rank 16

// Frag-major layout for all GEMM operands (1 KB per 16x32 fragment):
// frag idx = (row/16)*(K/32) + (k/32); lane l holds row = 16*(row/16)+(l&15),
// k = 32*(k/32) + (l>>4)*8 .. +7, at frag*512 + l*8 (u16).
// One global_load_dwordx4 at base + l*16 = one MFMA operand, fully coalesced.
// This also makes each fragment a contiguous 1 KB => one wave-wide
// global_load_lds (16 B/lane) stages exactly one fragment into linear LDS.

// ---------- helpers ----------
__device__ __forceinline__ u16 f2bf(float f) {
  unsigned u = __float_as_uint(f);
  u += 0x7fffu + ((u >> 16) & 1u);   // round-to-nearest-even
  return (u16)(u >> 16);
}
__device__ __forceinline__ float bflo(unsigned u) { return __uint_as_float(u << 16); }
__device__ __forceinline__ float bfhi(unsigned u) { return __uint_as_float(u & 0xffff0000u); }

// ---------- zero amax slots (ws poisoned 0xAA each launch) ----------
__global__ void zero_kernel(unsigned* amax) {
  if (threadIdx.x < 2) amax[threadIdx.x] = 0u;
}

// ---------- fused absmax of both weight tensors ----------
__global__ void absmax2_kernel(const float* __restrict__ wa, const float* __restrict__ wb,
                               long long n4, unsigned* __restrict__ out) {
  int which = blockIdx.x & 1;
  const float* w = which ? wb : wa;
  long long i = (long long)(blockIdx.x >> 1) * blockDim.x + threadIdx.x;
  long long stride = (long long)(gridDim.x >> 1) * blockDim.x;
  float m = 0.f;
  for (; i < n4; i += stride) {
    float4 v = ((const float4*)w)[i];
    m = fmaxf(m, fmaxf(fmaxf(fabsf(v.x), fabsf(v.y)), fmaxf(fabsf(v.z), fabsf(v.w))));
  }
#pragma unroll
  for (int o = 32; o > 0; o >>= 1) m = fmaxf(m, __shfl_xor(m, o, 64));
  __shared__ float sm[4];
  int lane = threadIdx.x & 63, wv = threadIdx.x >> 6;
  if (lane == 0) sm[wv] = m;
  __syncthreads();
  if (threadIdx.x == 0) {
    float mm = fmaxf(fmaxf(sm[0], sm[1]), fmaxf(sm[2], sm[3]));
    atomicMax(out + which, __float_as_uint(mm));   // nonneg: uint order == float order
  }
}

// ---------- packing, dst-major: coalesced 16B writes, gathered 32B reads ----------
// dst chunk d: lane-part l = d&63, frag = d>>6; row = (frag/nkc)*16 + (l&15),
// k8 = (frag%nkc)*4 + (l>>4); src = row*(K/8) + k8 (32B contiguous fp32).
__device__ __forceinline__ void pack_q(const float* __restrict__ w, u16* __restrict__ dst,
                                       long long d, int nkc, int kc3, float inv, float scale) {
  int l = (int)(d & 63);
  long long frag = d >> 6;
  long long m = (frag / nkc) * 16 + (l & 15);
  long long k8 = (frag % nkc) * 4 + (l >> 4);
  const float4* s = (const float4*)(w + ((m << kc3) + k8) * 8);
  float4 a = s[0], b = s[1];
  union { u16 h[8]; uint4 v; } o;
  o.h[0] = f2bf(fminf(fmaxf(rintf(a.x * inv), -128.f), 127.f) * scale);
  o.h[1] = f2bf(fminf(fmaxf(rintf(a.y * inv), -128.f), 127.f) * scale);
  o.h[2] = f2bf(fminf(fmaxf(rintf(a.z * inv), -128.f), 127.f) * scale);
  o.h[3] = f2bf(fminf(fmaxf(rintf(a.w * inv), -128.f), 127.f) * scale);
  o.h[4] = f2bf(fminf(fmaxf(rintf(b.x * inv), -128.f), 127.f) * scale);
  o.h[5] = f2bf(fminf(fmaxf(rintf(b.y * inv), -128.f), 127.f) * scale);
  o.h[6] = f2bf(fminf(fmaxf(rintf(b.z * inv), -128.f), 127.f) * scale);
  o.h[7] = f2bf(fminf(fmaxf(rintf(b.w * inv), -128.f), 127.f) * scale);
  ((uint4*)dst)[d] = o.v;
}
__device__ __forceinline__ void pack_c(const float* __restrict__ x, u16* __restrict__ dst,
                                       long long d, int nkc, int kc3) {
  int l = (int)(d & 63);
  long long frag = d >> 6;
  long long m = (frag / nkc) * 16 + (l & 15);
  long long k8 = (frag % nkc) * 4 + (l >> 4);
  const float4* s = (const float4*)(x + ((m << kc3) + k8) * 8);
  float4 a = s[0], b = s[1];
  union { u16 h[8]; uint4 v; } o;
  o.h[0] = f2bf(a.x); o.h[1] = f2bf(a.y); o.h[2] = f2bf(a.z); o.h[3] = f2bf(a.w);
  o.h[4] = f2bf(b.x); o.h[5] = f2bf(b.y); o.h[6] = f2bf(b.z); o.h[7] = f2bf(b.w);
  ((uint4*)dst)[d] = o.v;
}

__global__ void pack_all_kernel(const float* __restrict__ wfc, const float* __restrict__ wpr,
                                const float* __restrict__ x, const unsigned* __restrict__ amax,
                                u16* __restrict__ qfc, u16* __restrict__ qpr, u16* __restrict__ xb,
                                long long nfc, long long npr, long long nx, int kfc, int kpr, int kx) {
  float am0 = __uint_as_float(amax[0]);
  float am1 = __uint_as_float(amax[1]);
  float sc0 = am0 * (1.0f / 127.0f), in0 = 127.0f / am0;
  float sc1 = am1 * (1.0f / 127.0f), in1 = 127.0f / am1;
  long long i = (long long)blockIdx.x * blockDim.x + threadIdx.x;
  long long stride = (long long)gridDim.x * blockDim.x;
  long long tot = nfc + npr + nx;
  for (; i < tot; i += stride) {
    if (i < nfc)            pack_q(wfc, qfc, i, 1 << (kfc - 2), kfc, in0, sc0);
    else if (i < nfc + npr) pack_q(wpr, qpr, i - nfc, 1 << (kpr - 2), kpr, in1, sc1);
    else                    pack_c(x, xb, i - nfc - npr, 1 << (kx - 2), kx);
  }
}

// ---------- LoRA t = X(packed bf16) @ A^T(fp32): one wave per row, X read once ----------
__global__ void lora_t_kernel(const u16* __restrict__ X, const float* __restrict__ A,
                              float* __restrict__ T, int K) {
  int wv = threadIdx.x >> 6, lane = threadIdx.x & 63;
  long long row = (long long)blockIdx.x * 4 + wv;
  int nk = K >> 5;
  const u16* xp = X + ((row >> 4) * (long long)nk) * 512 + (row & 15) * 8;
  float acc[16];
#pragma unroll
  for (int r = 0; r < 16; ++r) acc[r] = 0.f;
  int nseg = K >> 3;
  for (int seg = lane; seg < nseg; seg += 64) {
    uint4 xv = *(const uint4*)(xp + (seg >> 2) * 512 + (seg & 3) * 128);
    float x0 = bflo(xv.x), x1 = bfhi(xv.x), x2 = bflo(xv.y), x3 = bfhi(xv.y);
    float x4 = bflo(xv.z), x5 = bfhi(xv.z), x6 = bflo(xv.w), x7 = bfhi(xv.w);
    int k = seg * 8;
#pragma unroll
    for (int r = 0; r < 16; ++r) {
      const float4* ar = (const float4*)(A + (long long)r * K + k);
      float4 a0 = ar[0], a1 = ar[1];
      acc[r] += x0 * a0.x + x1 * a0.y + x2 * a0.z + x3 * a0.w
              + x4 * a1.x + x5 * a1.y + x6 * a1.z + x7 * a1.w;
    }
  }
#pragma unroll
  for (int r = 0; r < 16; ++r) {
    float v = acc[r];
#pragma unroll
    for (int o = 32; o > 0; o >>= 1) v += __shfl_xor(v, o, 64);
    if (lane == r) T[row * 16 + r] = v;
  }
}

// ---------- async global->LDS staging helper ----------
typedef const __attribute__((address_space(1))) void* gas_ptr;
typedef __attribute__((address_space(3))) void* las_ptr;
__device__ __forceinline__ void stage_frag(const u16* __restrict__ g, u16* l) {
  // wave-wide: LDS gets base + lane*16B; global src is per-lane (g includes lane*16B)
  __builtin_amdgcn_global_load_lds((gas_ptr)g, (las_ptr)l, 16, 0, 0);
}

// ---------- main GEMM: m97 structure — LDS double-buffer via global_load_lds ----------
// 128x128 block, 256 threads = 4 waves (2x2), each wave 64x64 = 4x4 frags of 16x16x32 bf16.
// BK=32 (one frag-K per step). Per iter/wave: 4x global_load_lds (next tile, in flight
// across the MFMAs), 8x ds_read_b128 (linear, conflict-free), 16 MFMA, 1 barrier.
// LDS 32 KB/block -> up to 4 blocks/CU (vs 23% occupancy of the direct-global version),
// and load latency is absorbed by the LDS pipeline instead of per-wave registers.
template<int DO_GELU>
__global__ __launch_bounds__(256, 2)
void gemm_qlora_kernel(const u16* __restrict__ Apk, const u16* __restrict__ Bpk,
                       const float* __restrict__ bias, const float* __restrict__ T,
                       const float* __restrict__ Bl, void* __restrict__ outp,
                       int M, int N, int K) {
  const int tid = threadIdx.x;
  const int wave = tid >> 6, lane = tid & 63;
  const int quad = lane >> 4, m16 = lane & 15;

  const int per = (M >> 7) >> 3;          // bm tiles per XCD
  int j = blockIdx.x & 7, t = blockIdx.x >> 3;
  int bm = j * per + (t & (per - 1));
  int bn = t / per;

  const int wm = (wave >> 1) * 64, wn = (wave & 1) * 64;
  const int nk = K >> 5;

  __shared__ u16 lds[2][16][512];         // [buf][frag: 0-7 = A rows, 8-15 = B rows][1 KB]

  // staging: wave w stages A frag-rows {2w,2w+1} and B frag-rows {2w,2w+1}
  const u16* Ag0 = Apk + ((size_t)(bm * 8 + wave * 2)     * nk) * 512 + lane * 8;
  const u16* Ag1 = Apk + ((size_t)(bm * 8 + wave * 2 + 1) * nk) * 512 + lane * 8;
  const u16* Bg0 = Bpk + ((size_t)(bn * 8 + wave * 2)     * nk) * 512 + lane * 8;
  const u16* Bg1 = Bpk + ((size_t)(bn * 8 + wave * 2 + 1) * nk) * 512 + lane * 8;

  floatx4 acc[4][4] = {};

  // prologue: stage kt=0 into buf 0
  stage_frag(Ag0, &lds[0][wave * 2][0]);
  stage_frag(Ag1, &lds[0][wave * 2 + 1][0]);
  stage_frag(Bg0, &lds[0][8 + wave * 2][0]);
  stage_frag(Bg1, &lds[0][8 + wave * 2 + 1][0]);
  __syncthreads();                        // drains vmcnt -> buf0 ready

  const u16* la = &lds[0][(wave >> 1) * 4][0] + (size_t)lane * 8;
  const u16* lb = &lds[0][8 + (wave & 1) * 4][0] + (size_t)lane * 8;
  const size_t bufs = 16 * 512;           // u16 per buffer

#pragma unroll 1
  for (int kt = 0; kt < nk; ++kt) {
    const int cur = kt & 1;
    if (kt + 1 < nk) {                    // issue next-tile loads; they fly across the MFMAs
      const int nb = cur ^ 1;
      const size_t ko = (size_t)(kt + 1) * 512;
      stage_frag(Ag0 + ko, &lds[nb][wave * 2][0]);
      stage_frag(Ag1 + ko, &lds[nb][wave * 2 + 1][0]);
      stage_frag(Bg0 + ko, &lds[nb][8 + wave * 2][0]);
      stage_frag(Bg1 + ko, &lds[nb][8 + wave * 2 + 1][0]);
    }
    bf16x8 av[4], bv[4];
#pragma unroll
    for (int i = 0; i < 4; ++i) {
      av[i] = *(const bf16x8*)(la + cur * bufs + i * 512);
      bv[i] = *(const bf16x8*)(lb + cur * bufs + i * 512);
    }
#pragma unroll
    for (int mt = 0; mt < 4; ++mt)
#pragma unroll
      for (int nt = 0; nt < 4; ++nt)
        acc[mt][nt] = __builtin_amdgcn_mfma_f32_16x16x32_bf16(av[mt], bv[nt], acc[mt][nt], 0, 0, 0);
    __syncthreads();                      // waves done reading buf[cur]; staged loads drained
  }

  // epilogue: C/D layout row=(lane>>4)*4+reg, col=lane&15
  const float* Trow = T + (size_t)bm * 128 * 16;
  const float* Blrow = Bl + (size_t)bn * 128 * 16;
#pragma unroll
  for (int mt = 0; mt < 4; ++mt) {
#pragma unroll
    for (int r = 0; r < 4; ++r) {
      int ml = wm + mt * 16 + quad * 4 + r;
      size_t gm = (size_t)bm * 128 + ml;
      const float4* tv = (const float4*)(Trow + (size_t)ml * 16);
      float4 ta = tv[0], tb = tv[1], tc = tv[2], td = tv[3];
#pragma unroll
      for (int nt = 0; nt < 4; ++nt) {
        int nl = wn + nt * 16 + m16;
        size_t gn = (size_t)bn * 128 + nl;
        const float4* bv4 = (const float4*)(Blrow + (size_t)nl * 16);
        float4 ba = bv4[0], bb = bv4[1], bc = bv4[2], bd = bv4[3];
        float lora = ta.x * ba.x + ta.y * ba.y + ta.z * ba.z + ta.w * ba.w
                   + tb.x * bb.x + tb.y * bb.y + tb.z * bb.z + tb.w * bb.w
                   + tc.x * bc.x + tc.y * bc.y + tc.z * bc.z + tc.w * bc.w
                   + td.x * bd.x + td.y * bd.y + td.z * bd.z + td.w * bd.w;
        float v = acc[mt][nt][r] + bias[gn] + LORA_SCALING * lora;
        if (DO_GELU) {
          float g = 0.5f * v * (1.0f + erff(v * 0.70710678118654752f));
          size_t dst = ((gm >> 4) * (size_t)(N >> 5) + (gn >> 5)) * 512
                     + (gm & 15) * 8 + (((gn >> 3) & 3) << 7) + (gn & 7);
          ((u16*)outp)[dst] = f2bf(g);
        } else {
          ((float*)outp)[gm * (size_t)N + gn] = v;
        }
      }
    }
  }
}

// ---------- launch ----------
extern "C" void kernel_launch(void* const* d_in, const int* in_sizes, int n_in,
                              void* d_out, int out_size, void* d_ws, size_t ws_size,
                              hipStream_t stream) {
  const float* x    = (const float*)d_in[0];
  const float* W_fc = (const float*)d_in[1];
  const float* b_fc = (const float*)d_in[2];
  const float* A_fc = (const float*)d_in[3];
  const float* B_fc = (const float*)d_in[4];
  const float* W_pr = (const float*)d_in[5];
  const float* b_pr = (const float*)d_in[6];
  const float* A_pr = (const float*)d_in[7];
  const float* B_pr = (const float*)d_in[8];
  float* out = (float*)d_out;

  const int F = in_sizes[2];                 // 4096
  const int D = in_sizes[6];                 // 1024
  const int M = in_sizes[0] / D;             // 8192
  int dsh = 0; while ((1 << dsh) < D) ++dsh;
  int fsh = 0; while ((1 << fsh) < F) ++fsh;

  const size_t PAD = 1 << 17;                // 256 KB pad per packed buf
  char* ws = (char*)d_ws;
  unsigned* amax = (unsigned*)ws;
  u16* wq_fc = (u16*)(ws + 1024);
  u16* wq_pr = wq_fc + (size_t)F * D + PAD;
  u16* xbf   = wq_pr + (size_t)D * F + PAD;
  u16* gbf   = xbf + (size_t)M * D + PAD;
  float* t1  = (float*)(gbf + (size_t)M * F + PAD);
  float* t2  = t1 + (size_t)M * 16;

  long long wfd4 = (long long)F * D / 4;
  long long wfd8 = (long long)F * D / 8;
  long long xch  = (long long)M * D / 8;

  zero_kernel<<<1, 64, 0, stream>>>(amax);
  absmax2_kernel<<<2048, 256, 0, stream>>>(W_fc, W_pr, wfd4, amax);
  pack_all_kernel<<<2048, 256, 0, stream>>>(W_fc, W_pr, x, amax, wq_fc, wq_pr, xbf,
                                            wfd8, wfd8, xch, dsh - 3, fsh - 3, dsh - 3);
  lora_t_kernel<<<M / 4, 256, 0, stream>>>(xbf, A_fc, t1, D);
  gemm_qlora_kernel<1><<<dim3((M / 128) * (F / 128)), 256, 0, stream>>>(
      xbf, wq_fc, b_fc, t1, B_fc, (void*)gbf, M, F, D);
  lora_t_kernel<<<M / 4, 256, 0, stream>>>(gbf, A_pr, t2, F);
  gemm_qlora_kernel<0><<<dim3((M / 128) * (D / 128)), 256, 0, stream>>>(
      gbf, wq_pr, b_pr, t2, B_pr, (void*)out, M, D, F);
}

// Round 6
// 696.542 us; speedup vs baseline: 1.0836x; 1.0397x over previous
//
#include <hip/hip_runtime.h>
#include <hip/hip_bf16.h>
#include <math.h>

typedef unsigned short u16;
typedef __bf16 bf16x8 __attribute__((ext_vector_type(8)));
typedef float floatx4 __attribute__((ext_vector_type(4)));

#define LORA_SCALING 2.0f   // alpha 32 / rank 16

// Frag-major layout for all GEMM operands (1 KB per 16x32 fragment):
// frag idx = (row/16)*(K/32) + (k/32); lane l holds row = 16*(row/16)+(l&15),
// k = 32*(k/32) + (l>>4)*8 .. +7, at frag*512 + l*8 (u16).
// One wave-wide global_load_lds (16 B/lane) stages exactly one fragment into
// linear LDS; ds_read_b128 at frag_base + lane*16 is conflict-free.

// counted waits + raw barrier (T4): never drain vmcnt in the main loop.
#define VMWAIT(n) asm volatile("s_waitcnt vmcnt(" #n ")" ::: "memory")
#define BARRIER() asm volatile("s_barrier" ::: "memory")

// ---------- helpers ----------
__device__ __forceinline__ u16 f2bf(float f) {
  unsigned u = __float_as_uint(f);
  u += 0x7fffu + ((u >> 16) & 1u);   // round-to-nearest-even
  return (u16)(u >> 16);
}
__device__ __forceinline__ float bflo(unsigned u) { return __uint_as_float(u << 16); }
__device__ __forceinline__ float bfhi(unsigned u) { return __uint_as_float(u & 0xffff0000u); }

// ---------- zero amax slots (ws poisoned 0xAA each launch) ----------
__global__ void zero_kernel(unsigned* amax) {
  if (threadIdx.x < 2) amax[threadIdx.x] = 0u;
}

// ---------- fused absmax of both weight tensors ----------
__global__ void absmax2_kernel(const float* __restrict__ wa, const float* __restrict__ wb,
                               long long n4, unsigned* __restrict__ out) {
  int which = blockIdx.x & 1;
  const float* w = which ? wb : wa;
  long long i = (long long)(blockIdx.x >> 1) * blockDim.x + threadIdx.x;
  long long stride = (long long)(gridDim.x >> 1) * blockDim.x;
  float m = 0.f;
  for (; i < n4; i += stride) {
    float4 v = ((const float4*)w)[i];
    m = fmaxf(m, fmaxf(fmaxf(fabsf(v.x), fabsf(v.y)), fmaxf(fabsf(v.z), fabsf(v.w))));
  }
#pragma unroll
  for (int o = 32; o > 0; o >>= 1) m = fmaxf(m, __shfl_xor(m, o, 64));
  __shared__ float sm[4];
  int lane = threadIdx.x & 63, wv = threadIdx.x >> 6;
  if (lane == 0) sm[wv] = m;
  __syncthreads();
  if (threadIdx.x == 0) {
    float mm = fmaxf(fmaxf(sm[0], sm[1]), fmaxf(sm[2], sm[3]));
    atomicMax(out + which, __float_as_uint(mm));   // nonneg: uint order == float order
  }
}

// ---------- packing, dst-major: coalesced 16B writes, gathered 32B reads ----------
__device__ __forceinline__ void pack_q(const float* __restrict__ w, u16* __restrict__ dst,
                                       long long d, int nkc, int kc3, float inv, float scale) {
  int l = (int)(d & 63);
  long long frag = d >> 6;
  long long m = (frag / nkc) * 16 + (l & 15);
  long long k8 = (frag % nkc) * 4 + (l >> 4);
  const float4* s = (const float4*)(w + ((m << kc3) + k8) * 8);
  float4 a = s[0], b = s[1];
  union { u16 h[8]; uint4 v; } o;
  o.h[0] = f2bf(fminf(fmaxf(rintf(a.x * inv), -128.f), 127.f) * scale);
  o.h[1] = f2bf(fminf(fmaxf(rintf(a.y * inv), -128.f), 127.f) * scale);
  o.h[2] = f2bf(fminf(fmaxf(rintf(a.z * inv), -128.f), 127.f) * scale);
  o.h[3] = f2bf(fminf(fmaxf(rintf(a.w * inv), -128.f), 127.f) * scale);
  o.h[4] = f2bf(fminf(fmaxf(rintf(b.x * inv), -128.f), 127.f) * scale);
  o.h[5] = f2bf(fminf(fmaxf(rintf(b.y * inv), -128.f), 127.f) * scale);
  o.h[6] = f2bf(fminf(fmaxf(rintf(b.z * inv), -128.f), 127.f) * scale);
  o.h[7] = f2bf(fminf(fmaxf(rintf(b.w * inv), -128.f), 127.f) * scale);
  ((uint4*)dst)[d] = o.v;
}
__device__ __forceinline__ void pack_c(const float* __restrict__ x, u16* __restrict__ dst,
                                       long long d, int nkc, int kc3) {
  int l = (int)(d & 63);
  long long frag = d >> 6;
  long long m = (frag / nkc) * 16 + (l & 15);
  long long k8 = (frag % nkc) * 4 + (l >> 4);
  const float4* s = (const float4*)(x + ((m << kc3) + k8) * 8);
  float4 a = s[0], b = s[1];
  union { u16 h[8]; uint4 v; } o;
  o.h[0] = f2bf(a.x); o.h[1] = f2bf(a.y); o.h[2] = f2bf(a.z); o.h[3] = f2bf(a.w);
  o.h[4] = f2bf(b.x); o.h[5] = f2bf(b.y); o.h[6] = f2bf(b.z); o.h[7] = f2bf(b.w);
  ((uint4*)dst)[d] = o.v;
}

__global__ void pack_all_kernel(const float* __restrict__ wfc, const float* __restrict__ wpr,
                                const float* __restrict__ x, const unsigned* __restrict__ amax,
                                u16* __restrict__ qfc, u16* __restrict__ qpr, u16* __restrict__ xb,
                                long long nfc, long long npr, long long nx, int kfc, int kpr, int kx) {
  float am0 = __uint_as_float(amax[0]);
  float am1 = __uint_as_float(amax[1]);
  float sc0 = am0 * (1.0f / 127.0f), in0 = 127.0f / am0;
  float sc1 = am1 * (1.0f / 127.0f), in1 = 127.0f / am1;
  long long i = (long long)blockIdx.x * blockDim.x + threadIdx.x;
  long long stride = (long long)gridDim.x * blockDim.x;
  long long tot = nfc + npr + nx;
  for (; i < tot; i += stride) {
    if (i < nfc)            pack_q(wfc, qfc, i, 1 << (kfc - 2), kfc, in0, sc0);
    else if (i < nfc + npr) pack_q(wpr, qpr, i - nfc, 1 << (kpr - 2), kpr, in1, sc1);
    else                    pack_c(x, xb, i - nfc - npr, 1 << (kx - 2), kx);
  }
}

// ---------- LoRA t = X(packed bf16) @ A^T(fp32): one wave per row, X read once ----------
__global__ void lora_t_kernel(const u16* __restrict__ X, const float* __restrict__ A,
                              float* __restrict__ T, int K) {
  int wv = threadIdx.x >> 6, lane = threadIdx.x & 63;
  long long row = (long long)blockIdx.x * 4 + wv;
  int nk = K >> 5;
  const u16* xp = X + ((row >> 4) * (long long)nk) * 512 + (row & 15) * 8;
  float acc[16];
#pragma unroll
  for (int r = 0; r < 16; ++r) acc[r] = 0.f;
  int nseg = K >> 3;
  for (int seg = lane; seg < nseg; seg += 64) {
    uint4 xv = *(const uint4*)(xp + (seg >> 2) * 512 + (seg & 3) * 128);
    float x0 = bflo(xv.x), x1 = bfhi(xv.x), x2 = bflo(xv.y), x3 = bfhi(xv.y);
    float x4 = bflo(xv.z), x5 = bfhi(xv.z), x6 = bflo(xv.w), x7 = bfhi(xv.w);
    int k = seg * 8;
#pragma unroll
    for (int r = 0; r < 16; ++r) {
      const float4* ar = (const float4*)(A + (long long)r * K + k);
      float4 a0 = ar[0], a1 = ar[1];
      acc[r] += x0 * a0.x + x1 * a0.y + x2 * a0.z + x3 * a0.w
              + x4 * a1.x + x5 * a1.y + x6 * a1.z + x7 * a1.w;
    }
  }
#pragma unroll
  for (int r = 0; r < 16; ++r) {
    float v = acc[r];
#pragma unroll
    for (int o = 32; o > 0; o >>= 1) v += __shfl_xor(v, o, 64);
    if (lane == r) T[row * 16 + r] = v;
  }
}

// ---------- async global->LDS staging helper ----------
typedef const __attribute__((address_space(1))) void* gas_ptr;
typedef __attribute__((address_space(3))) void* las_ptr;
__device__ __forceinline__ void stage_frag(const u16* __restrict__ g, u16* l) {
  __builtin_amdgcn_global_load_lds((gas_ptr)g, (las_ptr)l, 16, 0, 0);
}

// ---------- main GEMM: 4-buffer LDS ring, prefetch distance 3, counted vmcnt ----------
// 128x128 block, 256 threads = 4 waves (2x2), each wave 64x64 = 4x4 frags of 16x16x32 bf16.
// Window kt: stage tile kt+3 (4 gload_lds) | ds_read+16 MFMA on tile kt |
// s_waitcnt vmcnt(8) (tile kt+1 resident; 2 tiles stay IN FLIGHT across the barrier) |
// raw s_barrier. Never vmcnt(0) in the loop (T4, m218: +38-73% vs drain).
// Overwrite safety: buf[(kt+3)&3] was last READ in window kt-1, one barrier back.
// Read safety: wave's own vmcnt(8) before barrier_kt+1 covers its tile-(kt+1) frags.
template<int DO_GELU>
__global__ __launch_bounds__(256, 2)
void gemm_qlora_kernel(const u16* __restrict__ Apk, const u16* __restrict__ Bpk,
                       const float* __restrict__ bias, const float* __restrict__ T,
                       const float* __restrict__ Bl, void* __restrict__ outp,
                       int M, int N, int K) {
  const int tid = threadIdx.x;
  const int wave = tid >> 6, lane = tid & 63;
  const int quad = lane >> 4, m16 = lane & 15;

  const int per = (M >> 7) >> 3;          // bm tiles per XCD
  int j = blockIdx.x & 7, t = blockIdx.x >> 3;
  int bm = j * per + (t & (per - 1));
  int bn = t / per;

  const int wm = (wave >> 1) * 64, wn = (wave & 1) * 64;
  const int nk = K >> 5;

  __shared__ u16 lds[4][16][512];         // 64 KB ring: [buf][frag 0-7=A, 8-15=B][1 KB]

  // staging: wave w stages A frag-rows {2w,2w+1} and B frag-rows {2w,2w+1}
  const u16* Ag0 = Apk + ((size_t)(bm * 8 + wave * 2)     * nk) * 512 + lane * 8;
  const u16* Ag1 = Apk + ((size_t)(bm * 8 + wave * 2 + 1) * nk) * 512 + lane * 8;
  const u16* Bg0 = Bpk + ((size_t)(bn * 8 + wave * 2)     * nk) * 512 + lane * 8;
  const u16* Bg1 = Bpk + ((size_t)(bn * 8 + wave * 2 + 1) * nk) * 512 + lane * 8;

  floatx4 acc[4][4] = {};

  // prologue: stage tiles 0,1,2 (12 loads in flight)
#pragma unroll
  for (int pt = 0; pt < 3; ++pt) {
    const size_t ko = (size_t)pt * 512;
    stage_frag(Ag0 + ko, &lds[pt][wave * 2][0]);
    stage_frag(Ag1 + ko, &lds[pt][wave * 2 + 1][0]);
    stage_frag(Bg0 + ko, &lds[pt][8 + wave * 2][0]);
    stage_frag(Bg1 + ko, &lds[pt][8 + wave * 2 + 1][0]);
  }
  VMWAIT(8);                              // tile 0 resident (tiles 1,2 in flight)
  BARRIER();

  const int aoff = (wave >> 1) * 4, boff = 8 + (wave & 1) * 4;

#define COMPUTE_TILE(KT)                                                        \
  {                                                                             \
    const u16* la = &lds[(KT) & 3][aoff][0] + (size_t)lane * 8;                 \
    const u16* lb = &lds[(KT) & 3][boff][0] + (size_t)lane * 8;                 \
    bf16x8 av[4], bv[4];                                                        \
    _Pragma("unroll")                                                           \
    for (int i = 0; i < 4; ++i) {                                               \
      av[i] = *(const bf16x8*)(la + i * 512);                                   \
      bv[i] = *(const bf16x8*)(lb + i * 512);                                   \
    }                                                                           \
    _Pragma("unroll")                                                           \
    for (int mt = 0; mt < 4; ++mt)                                              \
      _Pragma("unroll")                                                         \
      for (int nt = 0; nt < 4; ++nt)                                            \
        acc[mt][nt] = __builtin_amdgcn_mfma_f32_16x16x32_bf16(av[mt], bv[nt],   \
                                                              acc[mt][nt], 0, 0, 0); \
  }

#pragma unroll 1
  for (int kt = 0; kt < nk - 3; ++kt) {
    const int nb = (kt + 3) & 3;
    const size_t ko = (size_t)(kt + 3) * 512;
    stage_frag(Ag0 + ko, &lds[nb][wave * 2][0]);
    stage_frag(Ag1 + ko, &lds[nb][wave * 2 + 1][0]);
    stage_frag(Bg0 + ko, &lds[nb][8 + wave * 2][0]);
    stage_frag(Bg1 + ko, &lds[nb][8 + wave * 2 + 1][0]);
    COMPUTE_TILE(kt);
    VMWAIT(8);                            // tile kt+1 resident; kt+2, kt+3 in flight
    BARRIER();
  }
  // tail: no more staging; unwind the in-flight count 8 -> 4 -> 0
  COMPUTE_TILE(nk - 3);
  VMWAIT(4);
  BARRIER();
  COMPUTE_TILE(nk - 2);
  VMWAIT(0);
  BARRIER();
  COMPUTE_TILE(nk - 1);
#undef COMPUTE_TILE

  // epilogue: C/D layout row=(lane>>4)*4+reg, col=lane&15
  const float* Trow = T + (size_t)bm * 128 * 16;
  const float* Blrow = Bl + (size_t)bn * 128 * 16;
#pragma unroll
  for (int mt = 0; mt < 4; ++mt) {
#pragma unroll
    for (int r = 0; r < 4; ++r) {
      int ml = wm + mt * 16 + quad * 4 + r;
      size_t gm = (size_t)bm * 128 + ml;
      const float4* tv = (const float4*)(Trow + (size_t)ml * 16);
      float4 ta = tv[0], tb = tv[1], tc = tv[2], td = tv[3];
#pragma unroll
      for (int nt = 0; nt < 4; ++nt) {
        int nl = wn + nt * 16 + m16;
        size_t gn = (size_t)bn * 128 + nl;
        const float4* bv4 = (const float4*)(Blrow + (size_t)nl * 16);
        float4 ba = bv4[0], bb = bv4[1], bc = bv4[2], bd = bv4[3];
        float lora = ta.x * ba.x + ta.y * ba.y + ta.z * ba.z + ta.w * ba.w
                   + tb.x * bb.x + tb.y * bb.y + tb.z * bb.z + tb.w * bb.w
                   + tc.x * bc.x + tc.y * bc.y + tc.z * bc.z + tc.w * bc.w
                   + td.x * bd.x + td.y * bd.y + td.z * bd.z + td.w * bd.w;
        float v = acc[mt][nt][r] + bias[gn] + LORA_SCALING * lora;
        if (DO_GELU) {
          float g = 0.5f * v * (1.0f + erff(v * 0.70710678118654752f));
          size_t dst = ((gm >> 4) * (size_t)(N >> 5) + (gn >> 5)) * 512
                     + (gm & 15) * 8 + (((gn >> 3) & 3) << 7) + (gn & 7);
          ((u16*)outp)[dst] = f2bf(g);
        } else {
          ((float*)outp)[gm * (size_t)N + gn] = v;
        }
      }
    }
  }
}

// ---------- launch ----------
extern "C" void kernel_launch(void* const* d_in, const int* in_sizes, int n_in,
                              void* d_out, int out_size, void* d_ws, size_t ws_size,
                              hipStream_t stream) {
  const float* x    = (const float*)d_in[0];
  const float* W_fc = (const float*)d_in[1];
  const float* b_fc = (const float*)d_in[2];
  const float* A_fc = (const float*)d_in[3];
  const float* B_fc = (const float*)d_in[4];
  const float* W_pr = (const float*)d_in[5];
  const float* b_pr = (const float*)d_in[6];
  const float* A_pr = (const float*)d_in[7];
  const float* B_pr = (const float*)d_in[8];
  float* out = (float*)d_out;

  const int F = in_sizes[2];                 // 4096
  const int D = in_sizes[6];                 // 1024
  const int M = in_sizes[0] / D;             // 8192
  int dsh = 0; while ((1 << dsh) < D) ++dsh;
  int fsh = 0; while ((1 << fsh) < F) ++fsh;

  const size_t PAD = 1 << 17;                // 256 KB pad per packed buf
  char* ws = (char*)d_ws;
  unsigned* amax = (unsigned*)ws;
  u16* wq_fc = (u16*)(ws + 1024);
  u16* wq_pr = wq_fc + (size_t)F * D + PAD;
  u16* xbf   = wq_pr + (size_t)D * F + PAD;
  u16* gbf   = xbf + (size_t)M * D + PAD;
  float* t1  = (float*)(gbf + (size_t)M * F + PAD);
  float* t2  = t1 + (size_t)M * 16;

  long long wfd4 = (long long)F * D / 4;
  long long wfd8 = (long long)F * D / 8;
  long long xch  = (long long)M * D / 8;

  zero_kernel<<<1, 64, 0, stream>>>(amax);
  absmax2_kernel<<<2048, 256, 0, stream>>>(W_fc, W_pr, wfd4, amax);
  pack_all_kernel<<<2048, 256, 0, stream>>>(W_fc, W_pr, x, amax, wq_fc, wq_pr, xbf,
                                            wfd8, wfd8, xch, dsh - 3, fsh - 3, dsh - 3);
  lora_t_kernel<<<M / 4, 256, 0, stream>>>(xbf, A_fc, t1, D);
  gemm_qlora_kernel<1><<<dim3((M / 128) * (F / 128)), 256, 0, stream>>>(
      xbf, wq_fc, b_fc, t1, B_fc, (void*)gbf, M, F, D);
  lora_t_kernel<<<M / 4, 256, 0, stream>>>(gbf, A_pr, t2, F);
  gemm_qlora_kernel<0><<<dim3((M / 128) * (D / 128)), 256, 0, stream>>>(
      gbf, wq_pr, b_pr, t2, B_pr, (void*)out, M, D, F);
}